// Round 3
// baseline (264.806 us; speedup 1.0000x reference)
//
#include <hip/hip_runtime.h>

#define NN 50000
#define NE 1600000
#define IN_CH 128
#define HEADS 4
#define OUT_CH 32
#define HC 128                  // HEADS*OUT_CH
#define NEG_SLOPE 0.2f
#define EPS 1e-9f
#define SEG 96                  // csr slots per dst (Poisson(32), +11 sigma)

#define FGRP 8                                   // fill dst-window groups (1/XCD)
#define DPG (NN / FGRP)                          // 6250 dst nodes per group
#define ROWS_PB 64                               // rows per MFMA proj block
#define PROJ_BLOCKS ((NN + ROWS_PB - 1) / ROWS_PB)   // 782
#define XPITCH 136                               // LDS x row pitch (shorts)

#define FILLA_BLOCKS ((NE / 8 + 255) / 256)      // 782: one scan, 8 edges/thr
#define QCAP 210000          // queue slots/group: mean 200K, sigma 418, +24sig
#define FB_EPB 2048                              // edges per fillB block
#define FB_BPG ((QCAP + FB_EPB - 1) / FB_EPB)    // 103
#define FB_BLOCKS (FGRP * FB_BPG)                // 824

#define ENC_NEG_INF 0x007FFFFFu

using bf16x8 = __attribute__((ext_vector_type(8))) short;
using f32x4  = __attribute__((ext_vector_type(4))) float;
using u16x8  = __attribute__((ext_vector_type(8))) unsigned short;

__device__ __forceinline__ float leaky(float v) {
    return v >= 0.0f ? v : NEG_SLOPE * v;
}
__device__ __forceinline__ unsigned short f2bf(float f) {   // RNE bf16
    unsigned u = __float_as_uint(f);
    return (unsigned short)((u + 0x7fffu + ((u >> 16) & 1u)) >> 16);
}
__device__ __forceinline__ float bf2f(unsigned short b) {
    return __uint_as_float((unsigned)b << 16);
}
__device__ __forceinline__ unsigned int fenc(float f) {     // order-preserving
    unsigned int u = __float_as_uint(f);
    return (u & 0x80000000u) ? ~u : (u | 0x80000000u);
}
__device__ __forceinline__ float fdec(unsigned int u) {
    return (u & 0x80000000u) ? __uint_as_float(u & 0x7fffffffu)
                             : __uint_as_float(~u);
}

// ----------------------------- init: gmax + W -> Wt_bf (transposed) ---------
__global__ __launch_bounds__(256) void k_init(unsigned int* __restrict__ gmax,
                                              const float* __restrict__ W,
                                              unsigned short* __restrict__ Wt_bf) {
    int i = blockIdx.x * 256 + threadIdx.x;
    if (i < HEADS) gmax[i] = ENC_NEG_INF;
    if (i < IN_CH * HC) {
        int k = i >> 7, n = i & 127;
        Wt_bf[n * IN_CH + k] = f2bf(W[i]);
    }
}

// -------- MFMA projection (+fused logits+gmax) & fill pass A (queue build) --
// blocks [0, PROJ_BLOCKS): 4 waves, wave w rows [n0+16w, n0+16w+16); fused
//   per-head gmax via wave-max -> LDS -> 4 atomicMax/block.
// blocks [PROJ_BLOCKS, +FILLA_BLOCKS): ONE scan of ei (was 8x). Each block
//   LDS-bins its 2048 edges by group g = d/DPG, reserves one contiguous queue
//   chunk per group (single global atomicAdd each), and writes packed
//   (d_local<<16 | s) u32 records. Queue writes are dense/full-line -> no
//   partial-line writeback thrash. The scatter into the 19.2MB csr region is
//   deferred to k_fillB where each XCD's L2 holds queue (0.84MB) + window
//   (2.4MB) with NO streaming evictor. (r0-r2 measured 60MB excess WRITE from
//   ei streaming through the same L2 as the dirty csr window; nt loads made
//   it worse: r1/r2 82.5->89us. All loads here are plain.)
__global__ __launch_bounds__(256) void k_proj_fillA(
        const float* __restrict__ x,
        const unsigned short* __restrict__ Wt_bf,
        const float* __restrict__ att_s, const float* __restrict__ att_d,
        unsigned short* __restrict__ h_bf,
        float* __restrict__ a_s, float* __restrict__ a_d,
        const int* __restrict__ ei,
        unsigned int* __restrict__ queue, int* __restrict__ qcnt,
        unsigned int* __restrict__ gmax) {
    const int tid = threadIdx.x;
    if (blockIdx.x >= PROJ_BLOCKS) {
        __shared__ int lcnt[FGRP];
        __shared__ int sbase[FGRP];
        const int fb = blockIdx.x - PROJ_BLOCKS;
        const int e0 = (fb * 256 + tid) * 8;
        const bool valid = e0 < NE;      // NE%8==0 -> whole 8-pack valid
        if (tid < FGRP) lcnt[tid] = 0;
        __syncthreads();
        int rank[8], grp[8];
        unsigned pk[8];
        if (valid) {
            const int4 d0 = *(const int4*)(ei + NE + e0);
            const int4 d1 = *(const int4*)(ei + NE + e0 + 4);
            const int4 s0 = *(const int4*)(ei + e0);
            const int4 s1 = *(const int4*)(ei + e0 + 4);
            const int d[8] = {d0.x, d0.y, d0.z, d0.w, d1.x, d1.y, d1.z, d1.w};
            const int s[8] = {s0.x, s0.y, s0.z, s0.w, s1.x, s1.y, s1.z, s1.w};
#pragma unroll
            for (int k = 0; k < 8; ++k) {
                const int g = d[k] / DPG;            // compiler magic-mul
                grp[k] = g;
                pk[k] = ((unsigned)(d[k] - g * DPG) << 16) | (unsigned)s[k];
                rank[k] = atomicAdd(&lcnt[g], 1);    // LDS atomic
            }
        }
        __syncthreads();
        if (tid < FGRP) sbase[tid] = atomicAdd(&qcnt[tid], lcnt[tid]);
        __syncthreads();
        if (valid) {
#pragma unroll
            for (int k = 0; k < 8; ++k)
                queue[(size_t)grp[k] * QCAP + sbase[grp[k]] + rank[k]] = pk[k];
        }
        return;
    }
    __shared__ short xs[ROWS_PB * XPITCH];
    __shared__ float gsm[4][4];                   // [wave][head]
    const int n0 = blockIdx.x * ROWS_PB;

#pragma unroll
    for (int it = 0; it < 8; ++it) {
        const int idx = it * 256 + tid;          // float4 index
        const int row = idx >> 5;                // 32 float4 per row
        const int k4 = idx & 31;
        float4 v = make_float4(0.f, 0.f, 0.f, 0.f);
        if (n0 + row < NN)
            v = *(const float4*)(x + (size_t)(n0 + row) * IN_CH + k4 * 4);
        short* p = &xs[row * XPITCH + k4 * 4];
        p[0] = (short)f2bf(v.x); p[1] = (short)f2bf(v.y);
        p[2] = (short)f2bf(v.z); p[3] = (short)f2bf(v.w);
    }
    __syncthreads();

    const int wave = tid >> 6;
    const int lane = tid & 63;
    const int quad = lane >> 4;
    const int m16 = lane & 15;
    const int wrow = wave * 16;

    bf16x8 a[4];
#pragma unroll
    for (int ks = 0; ks < 4; ++ks)
        a[ks] = *(const bf16x8*)&xs[(wrow + m16) * XPITCH + ks * 32 + quad * 8];

    const int row_base = n0 + wrow + quad * 4;
    float gmx[4];
#pragma unroll
    for (int hh = 0; hh < 4; ++hh) {
        float psh[4] = {0.f, 0.f, 0.f, 0.f};
        float pdh[4] = {0.f, 0.f, 0.f, 0.f};
#pragma unroll
        for (int c2 = 0; c2 < 2; ++c2) {
            const int ct = hh * 2 + c2;
            const unsigned short* wb = Wt_bf + (size_t)(ct * 16 + m16) * IN_CH + quad * 8;
            bf16x8 b0 = *(const bf16x8*)(wb);
            bf16x8 b1 = *(const bf16x8*)(wb + 32);
            bf16x8 b2 = *(const bf16x8*)(wb + 64);
            bf16x8 b3 = *(const bf16x8*)(wb + 96);
            f32x4 acc = {0.f, 0.f, 0.f, 0.f};
            acc = __builtin_amdgcn_mfma_f32_16x16x32_bf16(a[0], b0, acc, 0, 0, 0);
            acc = __builtin_amdgcn_mfma_f32_16x16x32_bf16(a[1], b1, acc, 0, 0, 0);
            acc = __builtin_amdgcn_mfma_f32_16x16x32_bf16(a[2], b2, acc, 0, 0, 0);
            acc = __builtin_amdgcn_mfma_f32_16x16x32_bf16(a[3], b3, acc, 0, 0, 0);
            const int col = ct * 16 + m16;
            const float asv = att_s[col];
            const float adv = att_d[col];
#pragma unroll
            for (int r = 0; r < 4; ++r) {
                const int n = row_base + r;
                if (n < NN) h_bf[(size_t)n * HC + col] = f2bf(acc[r]);
                psh[r] = fmaf(acc[r], asv, psh[r]);
                pdh[r] = fmaf(acc[r], adv, pdh[r]);
            }
        }
#pragma unroll
        for (int mk = 1; mk <= 8; mk <<= 1) {
#pragma unroll
            for (int r = 0; r < 4; ++r) {
                psh[r] += __shfl_xor(psh[r], mk, 64);
                pdh[r] += __shfl_xor(pdh[r], mk, 64);
            }
        }
        if (m16 == 0) {
#pragma unroll
            for (int r = 0; r < 4; ++r) {
                const int n = row_base + r;
                if (n < NN) {
                    a_s[n * HEADS + hh] = psh[r];
                    a_d[n * HEADS + hh] = pdh[r];
                }
            }
        }
        // wave-wide max of this head's logits (pad rows contribute 0.0 —
        // harmless: bound only needs to be an upper bound, cancels in alpha)
        float mx = fmaxf(fmaxf(psh[0], psh[1]), fmaxf(psh[2], psh[3]));
        mx = fmaxf(mx, __shfl_xor(mx, 16, 64));
        mx = fmaxf(mx, __shfl_xor(mx, 32, 64));
        gmx[hh] = mx;
    }
    if (lane == 0) {
        gsm[wave][0] = gmx[0]; gsm[wave][1] = gmx[1];
        gsm[wave][2] = gmx[2]; gsm[wave][3] = gmx[3];
    }
    __syncthreads();
    if (tid < 4) {
        float mm = fmaxf(fmaxf(gsm[0][tid], gsm[1][tid]),
                         fmaxf(gsm[2][tid], gsm[3][tid]));
        atomicMax(&gmax[tid], fenc(mm));
    }
}

// ------------------- fill pass B: dense queue -> csr window scatter ---------
// block b serves group f = b&7 (round-robin blockIdx->XCD pins group f to
// XCD (f)). XCD-local working set: queue slice 0.84MB (read once, dense) +
// csr window 2.4MB (dirty) + cnt slice 25KB = 3.3MB < 4MB L2. No streaming
// evictor -> each csr line written back exactly once.
__global__ __launch_bounds__(256) void k_fillB(const unsigned int* __restrict__ queue,
                                               const int* __restrict__ qcnt,
                                               int* __restrict__ cnt,
                                               int* __restrict__ csr_src) {
    const int f = blockIdx.x & (FGRP - 1);
    const int j = blockIdx.x >> 3;
    const int m = qcnt[f];
    const int base = j * FB_EPB + (int)threadIdx.x * 8;
    if (base >= m) return;
    const unsigned int* qf = queue + (size_t)f * QCAP;
    // base%8==0 and base<m<=QCAP (QCAP%8==0) -> safe to read full 8-pack
    const uint4 w0 = *(const uint4*)(qf + base);
    const uint4 w1 = *(const uint4*)(qf + base + 4);
    const unsigned w[8] = {w0.x, w0.y, w0.z, w0.w, w1.x, w1.y, w1.z, w1.w};
    const int lo = f * DPG;
#pragma unroll
    for (int k = 0; k < 8; ++k) {
        if (base + k < m) {
            const int s = (int)(w[k] & 0xFFFFu);
            const int d = (int)(w[k] >> 16) + lo;
            const int pos = atomicAdd(&cnt[d], 1);
            if (pos < SEG)                        // statistically never false
                csr_src[(size_t)d * SEG + pos] = s;
        }
    }
}

// ----------------------------------------------------- gather aggregation ---
// one wave per dst node; 16-lane quarter owns an edge (4 edges in flight);
// lane owns 8 channels (ushort8). Segment CSR: beg = n*SEG, end = beg+cnt[n].
// 2-deep rotated software pipeline: csr index loaded 2 iterations ahead,
// a_s / h row gathers issued 1 iteration ahead.
__global__ __launch_bounds__(256) void k_agg(const int* __restrict__ cnt,
                                             const int* __restrict__ csr_src,
                                             const unsigned short* __restrict__ h_bf,
                                             const float* __restrict__ a_s,
                                             const float* __restrict__ a_d,
                                             const unsigned int* __restrict__ gmax,
                                             const float* __restrict__ bias,
                                             float* __restrict__ out) {
    const int n = blockIdx.x * 4 + (threadIdx.x >> 6);
    const int lane = threadIdx.x & 63;
    if (n >= NN) return;
    const int q = lane >> 4;                      // quarter: owns edges i+q
    const int ql = lane & 15;                     // channels 8*ql .. 8*ql+7
    const int hd = ql >> 2;                       // head of those channels
    int dg = cnt[n];
    if (dg > SEG) dg = SEG;
    const int beg = n * SEG;
    const int end = beg + dg;

    const float ad_h = a_d[n * 4 + hd];
    const float bound = leaky(fdec(gmax[hd]) + ad_h);   // >= every edge score

    // self term (all 4 quads compute it -> pre-scale by 1/4; quad-reduce sums)
    float ev = 0.25f * __expf(leaky(a_s[n * 4 + hd] + ad_h) - bound);
    float denom = ev;
    const u16x8 hs = *(const u16x8*)(h_bf + (size_t)n * HC + 8 * ql);
    float acc[8];
#pragma unroll
    for (int k = 0; k < 8; ++k) acc[k] = ev * bf2f(hs[k]);

    // pipeline prologue: s0 (current), s1 (next); dummy = n (always valid)
    int i = beg + q;
    int s0v = (i < end)     ? csr_src[i]     : n;
    int s1v = (i + 4 < end) ? csr_src[i + 4] : n;
    float as0 = a_s[s0v * 4 + hd];
    u16x8 hv0 = *(const u16x8*)(h_bf + (size_t)s0v * HC + 8 * ql);

    for (; i < end; i += 4) {
        // prefetch: csr 2 ahead, a_s/h 1 ahead
        const int s2v = (i + 8 < end) ? csr_src[i + 8] : n;
        const float as1 = a_s[s1v * 4 + hd];
        const u16x8 hv1 = *(const u16x8*)(h_bf + (size_t)s1v * HC + 8 * ql);
        // consume current
        const float e = __expf(leaky(as0 + ad_h) - bound);
        denom += e;
#pragma unroll
        for (int k = 0; k < 8; ++k)
            acc[k] = fmaf(e, bf2f(hv0[k]), acc[k]);
        // rotate
        as0 = as1; hv0 = hv1; s1v = s2v;
    }
#pragma unroll
    for (int k = 0; k < 8; ++k) {
        acc[k] += __shfl_xor(acc[k], 16, 64);
        acc[k] += __shfl_xor(acc[k], 32, 64);
    }
    denom += __shfl_xor(denom, 16, 64);
    denom += __shfl_xor(denom, 32, 64);

    if (q == 0) {
        const float inv = 1.0f / (denom + EPS);
        float* o = out + (size_t)n * HC + 8 * ql;
        const float* b = bias + 8 * ql;
        f32x4 o0, o1;
        o0[0] = acc[0] * inv + b[0]; o0[1] = acc[1] * inv + b[1];
        o0[2] = acc[2] * inv + b[2]; o0[3] = acc[3] * inv + b[3];
        o1[0] = acc[4] * inv + b[4]; o1[1] = acc[5] * inv + b[5];
        o1[2] = acc[6] * inv + b[6]; o1[3] = acc[7] * inv + b[7];
        __builtin_nontemporal_store(o0, (f32x4*)(o));
        __builtin_nontemporal_store(o1, (f32x4*)(o + 4));
    }
}

// ---------------------------------------------------------------------------
extern "C" void kernel_launch(void* const* d_in, const int* in_sizes, int n_in,
                              void* d_out, int out_size, void* d_ws, size_t ws_size,
                              hipStream_t stream) {
    const float* x     = (const float*)d_in[0];
    const int*   ei    = (const int*)d_in[1];
    const float* W     = (const float*)d_in[2];
    const float* att_s = (const float*)d_in[3];
    const float* att_d = (const float*)d_in[4];
    const float* bias  = (const float*)d_in[5];
    float* out = (float*)d_out;

    char* ws = (char*)d_ws;
    int*   cnt     = (int*)ws;    ws += (size_t)NN * 4;                // 200 KB
    int*   qcnt    = (int*)ws;    ws += 64;                            // 8 used
    unsigned int* gmax = (unsigned int*)ws; ws += 64;
    int*   csr_src = (int*)ws;    ws += (size_t)NN * SEG * 4;          // 19.2 MB
    unsigned short* h_bf = (unsigned short*)ws; ws += (size_t)NN * HC * 2; // 12.8 MB
    float* a_s     = (float*)ws;  ws += (size_t)NN * HEADS * 4;        // 0.8 MB
    float* a_d     = (float*)ws;  ws += (size_t)NN * HEADS * 4;        // 0.8 MB
    unsigned short* Wt_bf = (unsigned short*)ws; ws += (size_t)IN_CH * HC * 2; // 32 KB
    unsigned int* queue = (unsigned int*)ws; ws += (size_t)FGRP * QCAP * 4; // 6.7 MB

    hipMemsetAsync(cnt, 0, (size_t)NN * 4 + 64, stream);   // cnt + qcnt
    k_init      <<<(IN_CH * HC + 255) / 256, 256, 0, stream>>>(gmax, W, Wt_bf);
    k_proj_fillA<<<PROJ_BLOCKS + FILLA_BLOCKS, 256, 0, stream>>>(
        x, Wt_bf, att_s, att_d, h_bf, a_s, a_d, ei, queue, qcnt, gmax);
    k_fillB     <<<FB_BLOCKS, 256, 0, stream>>>(queue, qcnt, cnt, csr_src);
    k_agg       <<<(NN + 3) / 4, 256, 0, stream>>>(cnt, csr_src, h_bf, a_s, a_d,
                                                   gmax, bias, out);
}

// Round 4
// 220.085 us; speedup vs baseline: 1.2032x; 1.2032x over previous
//
#include <hip/hip_runtime.h>

#define NN 50000
#define NE 1600000
#define IN_CH 128
#define HEADS 4
#define OUT_CH 32
#define HC 128                  // HEADS*OUT_CH
#define NEG_SLOPE 0.2f
#define EPS 1e-9f
#define SEG 96                  // csr slots per dst (Poisson(32), +11 sigma)

#define FGRP 8                                   // fill dst-window groups
#define DPG (NN / FGRP)                          // 6250 dst nodes per group
#define FILL_BPG ((NE / 8 + 255) / 256)          // 782 blocks per group (8 e/thr)
#define ROWS_PB 64                               // rows per MFMA proj block
#define PROJ_BLOCKS ((NN + ROWS_PB - 1) / ROWS_PB)   // 782
#define XPITCH 136                               // LDS x row pitch (shorts)
#define INIT_BLOCKS ((NN + 255) / 256)           // 196 (covers cnt zeroing)
#define GMAX_BLOCKS ((NN + 255) / 256)           // 196

#define ENC_NEG_INF 0x007FFFFFu

using bf16x8 = __attribute__((ext_vector_type(8))) short;
using f32x4  = __attribute__((ext_vector_type(4))) float;
using u16x8  = __attribute__((ext_vector_type(8))) unsigned short;

__device__ __forceinline__ float leaky(float v) {
    return v >= 0.0f ? v : NEG_SLOPE * v;
}
__device__ __forceinline__ unsigned short f2bf(float f) {   // RNE bf16
    unsigned u = __float_as_uint(f);
    return (unsigned short)((u + 0x7fffu + ((u >> 16) & 1u)) >> 16);
}
__device__ __forceinline__ float bf2f(unsigned short b) {
    return __uint_as_float((unsigned)b << 16);
}
__device__ __forceinline__ unsigned int fenc(float f) {     // order-preserving
    unsigned int u = __float_as_uint(f);
    return (u & 0x80000000u) ? ~u : (u | 0x80000000u);
}
__device__ __forceinline__ float fdec(unsigned int u) {
    return (u & 0x80000000u) ? __uint_as_float(u & 0x7fffffffu)
                             : __uint_as_float(~u);
}

// ------------- init: cnt zero + gmax + W -> Wt_bf (transposed) --------------
// grid covers NN so the 200KB cnt memset is folded in (one launch fewer;
// ~10us inter-launch overhead measured across r0-r3 accounting).
__global__ __launch_bounds__(256) void k_init(int* __restrict__ cnt,
                                              unsigned int* __restrict__ gmax,
                                              const float* __restrict__ W,
                                              unsigned short* __restrict__ Wt_bf) {
    int i = blockIdx.x * 256 + threadIdx.x;
    if (i < HEADS) gmax[i] = ENC_NEG_INF;
    if (i < NN) cnt[i] = 0;
    if (i < IN_CH * HC) {
        int k = i >> 7, n = i & 127;
        Wt_bf[n * IN_CH + k] = f2bf(W[i]);
    }
}

// -------- MFMA projection (+fused logits) & segment-cursor CSR fill ---------
// r0 structure restored exactly (fastest measured: 82.5us; r2's gmax fusion
// cost +6.7us via VGPR 36->44 / occupancy 67->48%; r3's queue split cost more
// than it saved). One delta: csr entries are u16 (src < 65536) — halves the
// CSR region to 9.6MB, halving the partial-dirty-line writeback thrash that
// made WRITE_SIZE 95MB vs ~30MB ideal.
// blocks [0, PROJ_BLOCKS): 4 waves, wave w rows [n0+16w, n0+16w+16).
// blocks [PROJ_BLOCKS, +FGRP*FILL_BPG): one-pass CSR build, group f = fb&7
//   writes only dst in [f*DPG,(f+1)*DPG) -> dirty window now ~1.2MB/group.
__global__ __launch_bounds__(256) void k_proj_fill(
        const float* __restrict__ x,
        const unsigned short* __restrict__ Wt_bf,
        const float* __restrict__ att_s, const float* __restrict__ att_d,
        unsigned short* __restrict__ h_bf,
        float* __restrict__ a_s, float* __restrict__ a_d,
        const int* __restrict__ ei, int* __restrict__ cnt,
        unsigned short* __restrict__ csr_src) {
    if (blockIdx.x >= PROJ_BLOCKS) {
        const int fb = blockIdx.x - PROJ_BLOCKS;
        const int f = fb & (FGRP - 1);
        const int bg = fb >> 3;
        const int e0 = (bg * 256 + (int)threadIdx.x) * 8;
        if (e0 >= NE) return;
        const int lo = f * DPG;
        const int4 d0 = *(const int4*)(ei + NE + e0);
        const int4 d1 = *(const int4*)(ei + NE + e0 + 4);
        const int4 s0 = *(const int4*)(ei + e0);
        const int4 s1 = *(const int4*)(ei + e0 + 4);
        const int d[8] = {d0.x, d0.y, d0.z, d0.w, d1.x, d1.y, d1.z, d1.w};
        const int s[8] = {s0.x, s0.y, s0.z, s0.w, s1.x, s1.y, s1.z, s1.w};
#pragma unroll
        for (int k = 0; k < 8; ++k) {
            if ((unsigned)(d[k] - lo) < (unsigned)DPG) {
                const int pos = atomicAdd(&cnt[d[k]], 1);
                if (pos < SEG)                    // statistically never false
                    csr_src[(size_t)d[k] * SEG + pos] = (unsigned short)s[k];
            }
        }
        return;
    }
    __shared__ short xs[ROWS_PB * XPITCH];
    const int tid = threadIdx.x;
    const int n0 = blockIdx.x * ROWS_PB;

#pragma unroll
    for (int it = 0; it < 8; ++it) {
        const int idx = it * 256 + tid;          // float4 index
        const int row = idx >> 5;                // 32 float4 per row
        const int k4 = idx & 31;
        float4 v = make_float4(0.f, 0.f, 0.f, 0.f);
        if (n0 + row < NN) v = *(const float4*)(x + (size_t)(n0 + row) * IN_CH + k4 * 4);
        short* p = &xs[row * XPITCH + k4 * 4];
        p[0] = (short)f2bf(v.x); p[1] = (short)f2bf(v.y);
        p[2] = (short)f2bf(v.z); p[3] = (short)f2bf(v.w);
    }
    __syncthreads();

    const int wave = tid >> 6;
    const int lane = tid & 63;
    const int quad = lane >> 4;
    const int m16 = lane & 15;
    const int wrow = wave * 16;

    bf16x8 a[4];
#pragma unroll
    for (int ks = 0; ks < 4; ++ks)
        a[ks] = *(const bf16x8*)&xs[(wrow + m16) * XPITCH + ks * 32 + quad * 8];

    const int row_base = n0 + wrow + quad * 4;
#pragma unroll
    for (int hh = 0; hh < 4; ++hh) {
        float psh[4] = {0.f, 0.f, 0.f, 0.f};
        float pdh[4] = {0.f, 0.f, 0.f, 0.f};
#pragma unroll
        for (int c2 = 0; c2 < 2; ++c2) {
            const int ct = hh * 2 + c2;
            const unsigned short* wb = Wt_bf + (size_t)(ct * 16 + m16) * IN_CH + quad * 8;
            bf16x8 b0 = *(const bf16x8*)(wb);
            bf16x8 b1 = *(const bf16x8*)(wb + 32);
            bf16x8 b2 = *(const bf16x8*)(wb + 64);
            bf16x8 b3 = *(const bf16x8*)(wb + 96);
            f32x4 acc = {0.f, 0.f, 0.f, 0.f};
            acc = __builtin_amdgcn_mfma_f32_16x16x32_bf16(a[0], b0, acc, 0, 0, 0);
            acc = __builtin_amdgcn_mfma_f32_16x16x32_bf16(a[1], b1, acc, 0, 0, 0);
            acc = __builtin_amdgcn_mfma_f32_16x16x32_bf16(a[2], b2, acc, 0, 0, 0);
            acc = __builtin_amdgcn_mfma_f32_16x16x32_bf16(a[3], b3, acc, 0, 0, 0);
            const int col = ct * 16 + m16;
            const float asv = att_s[col];
            const float adv = att_d[col];
#pragma unroll
            for (int r = 0; r < 4; ++r) {
                const int n = row_base + r;
                if (n < NN) h_bf[(size_t)n * HC + col] = f2bf(acc[r]);
                psh[r] = fmaf(acc[r], asv, psh[r]);
                pdh[r] = fmaf(acc[r], adv, pdh[r]);
            }
        }
#pragma unroll
        for (int mk = 1; mk <= 8; mk <<= 1) {
#pragma unroll
            for (int r = 0; r < 4; ++r) {
                psh[r] += __shfl_xor(psh[r], mk, 64);
                pdh[r] += __shfl_xor(pdh[r], mk, 64);
            }
        }
        if (m16 == 0) {
#pragma unroll
            for (int r = 0; r < 4; ++r) {
                const int n = row_base + r;
                if (n < NN) {
                    a_s[n * HEADS + hh] = psh[r];
                    a_d[n * HEADS + hh] = pdh[r];
                }
            }
        }
    }
}

// ------------------------------------ global per-head max of a_s ------------
__global__ __launch_bounds__(256) void k_gmax(const float* __restrict__ a_s,
                                              unsigned int* __restrict__ gmax) {
    const int n = blockIdx.x * 256 + threadIdx.x;
    float4 m4 = make_float4(-1e30f, -1e30f, -1e30f, -1e30f);
    if (n < NN) m4 = *(const float4*)(a_s + n * 4);
#pragma unroll
    for (int m = 32; m >= 1; m >>= 1) {
        m4.x = fmaxf(m4.x, __shfl_xor(m4.x, m, 64));
        m4.y = fmaxf(m4.y, __shfl_xor(m4.y, m, 64));
        m4.z = fmaxf(m4.z, __shfl_xor(m4.z, m, 64));
        m4.w = fmaxf(m4.w, __shfl_xor(m4.w, m, 64));
    }
    __shared__ float wm[4][4];
    const int wv = threadIdx.x >> 6;
    if ((threadIdx.x & 63) == 0) {
        wm[wv][0] = m4.x; wm[wv][1] = m4.y; wm[wv][2] = m4.z; wm[wv][3] = m4.w;
    }
    __syncthreads();
    if (threadIdx.x < 4) {
        float mm = fmaxf(fmaxf(wm[0][threadIdx.x], wm[1][threadIdx.x]),
                         fmaxf(wm[2][threadIdx.x], wm[3][threadIdx.x]));
        atomicMax(&gmax[threadIdx.x], fenc(mm));
    }
}

// ----------------------------------------------------- gather aggregation ---
// one wave per dst node; 16-lane quarter owns an edge (4 edges in flight);
// lane owns 8 channels (ushort8). Segment CSR (u16): beg = n*SEG, end=beg+cnt.
// 2-deep rotated software pipeline: csr index loaded 2 iterations ahead,
// a_s / h row gathers issued 1 iteration ahead. Measured r3: 74.5us,
// FETCH 250MB (L2-miss-BW bound on the random 256B h-row gathers).
__global__ __launch_bounds__(256) void k_agg(const int* __restrict__ cnt,
                                             const unsigned short* __restrict__ csr_src,
                                             const unsigned short* __restrict__ h_bf,
                                             const float* __restrict__ a_s,
                                             const float* __restrict__ a_d,
                                             const unsigned int* __restrict__ gmax,
                                             const float* __restrict__ bias,
                                             float* __restrict__ out) {
    const int n = blockIdx.x * 4 + (threadIdx.x >> 6);
    const int lane = threadIdx.x & 63;
    if (n >= NN) return;
    const int q = lane >> 4;                      // quarter: owns edges i+q
    const int ql = lane & 15;                     // channels 8*ql .. 8*ql+7
    const int hd = ql >> 2;                       // head of those channels
    int dg = cnt[n];
    if (dg > SEG) dg = SEG;
    const int beg = n * SEG;
    const int end = beg + dg;

    const float ad_h = a_d[n * 4 + hd];
    const float bound = leaky(fdec(gmax[hd]) + ad_h);   // >= every edge score

    // self term (all 4 quads compute it -> pre-scale by 1/4; quad-reduce sums)
    float ev = 0.25f * __expf(leaky(a_s[n * 4 + hd] + ad_h) - bound);
    float denom = ev;
    const u16x8 hs = *(const u16x8*)(h_bf + (size_t)n * HC + 8 * ql);
    float acc[8];
#pragma unroll
    for (int k = 0; k < 8; ++k) acc[k] = ev * bf2f(hs[k]);

    // pipeline prologue: s0 (current), s1 (next); dummy = n (always valid)
    int i = beg + q;
    int s0v = (i < end)     ? (int)csr_src[i]     : n;
    int s1v = (i + 4 < end) ? (int)csr_src[i + 4] : n;
    float as0 = a_s[s0v * 4 + hd];
    u16x8 hv0 = *(const u16x8*)(h_bf + (size_t)s0v * HC + 8 * ql);

    for (; i < end; i += 4) {
        // prefetch: csr 2 ahead, a_s/h 1 ahead
        const int s2v = (i + 8 < end) ? (int)csr_src[i + 8] : n;
        const float as1 = a_s[s1v * 4 + hd];
        const u16x8 hv1 = *(const u16x8*)(h_bf + (size_t)s1v * HC + 8 * ql);
        // consume current
        const float e = __expf(leaky(as0 + ad_h) - bound);
        denom += e;
#pragma unroll
        for (int k = 0; k < 8; ++k)
            acc[k] = fmaf(e, bf2f(hv0[k]), acc[k]);
        // rotate
        as0 = as1; hv0 = hv1; s1v = s2v;
    }
#pragma unroll
    for (int k = 0; k < 8; ++k) {
        acc[k] += __shfl_xor(acc[k], 16, 64);
        acc[k] += __shfl_xor(acc[k], 32, 64);
    }
    denom += __shfl_xor(denom, 16, 64);
    denom += __shfl_xor(denom, 32, 64);

    if (q == 0) {
        const float inv = 1.0f / (denom + EPS);
        float* o = out + (size_t)n * HC + 8 * ql;
        const float* b = bias + 8 * ql;
        f32x4 o0, o1;
        o0[0] = acc[0] * inv + b[0]; o0[1] = acc[1] * inv + b[1];
        o0[2] = acc[2] * inv + b[2]; o0[3] = acc[3] * inv + b[3];
        o1[0] = acc[4] * inv + b[4]; o1[1] = acc[5] * inv + b[5];
        o1[2] = acc[6] * inv + b[6]; o1[3] = acc[7] * inv + b[7];
        __builtin_nontemporal_store(o0, (f32x4*)(o));
        __builtin_nontemporal_store(o1, (f32x4*)(o + 4));
    }
}

// ---------------------------------------------------------------------------
extern "C" void kernel_launch(void* const* d_in, const int* in_sizes, int n_in,
                              void* d_out, int out_size, void* d_ws, size_t ws_size,
                              hipStream_t stream) {
    const float* x     = (const float*)d_in[0];
    const int*   ei    = (const int*)d_in[1];
    const float* W     = (const float*)d_in[2];
    const float* att_s = (const float*)d_in[3];
    const float* att_d = (const float*)d_in[4];
    const float* bias  = (const float*)d_in[5];
    float* out = (float*)d_out;

    char* ws = (char*)d_ws;
    int*   cnt     = (int*)ws;    ws += (size_t)NN * 4;                // 200 KB
    unsigned int* gmax = (unsigned int*)ws; ws += 64;
    unsigned short* csr_src = (unsigned short*)ws; ws += (size_t)NN * SEG * 2; // 9.6 MB
    unsigned short* h_bf = (unsigned short*)ws; ws += (size_t)NN * HC * 2; // 12.8 MB
    float* a_s     = (float*)ws;  ws += (size_t)NN * HEADS * 4;        // 0.8 MB
    float* a_d     = (float*)ws;  ws += (size_t)NN * HEADS * 4;        // 0.8 MB
    unsigned short* Wt_bf = (unsigned short*)ws; ws += (size_t)IN_CH * HC * 2; // 32 KB

    k_init     <<<INIT_BLOCKS, 256, 0, stream>>>(cnt, gmax, W, Wt_bf);
    k_proj_fill<<<PROJ_BLOCKS + FGRP * FILL_BPG, 256, 0, stream>>>(
        x, Wt_bf, att_s, att_d, h_bf, a_s, a_d, ei, cnt, csr_src);
    k_gmax     <<<GMAX_BLOCKS, 256, 0, stream>>>(a_s, gmax);
    k_agg      <<<(NN + 3) / 4, 256, 0, stream>>>(cnt, csr_src, h_bf, a_s, a_d,
                                                  gmax, bias, out);
}